// Round 17
// baseline (129.550 us; speedup 1.0000x reference)
//
#include <hip/hip_runtime.h>
#include <hip/hip_bf16.h>

#define NQ       131072     // 32*4096 queries
#define KC       1024       // codes
#define DIM      64
#define MARGIN_A 7.5e-5f    // acc-space: 1.2e-5 f32/split err + 2x1.5e-5 trunc + slack
#define RGRID    2048       // rescue grid (blocks)

typedef __attribute__((ext_vector_type(8)))  short s8bf;    // 8 bf16 (4 VGPRs)
typedef __attribute__((ext_vector_type(16))) float f32x16;  // 32x32 MFMA acc

union BF8 { s8bf v; unsigned short u[8]; };

__device__ __forceinline__ unsigned short f2bf_u(float f) {
    union { __hip_bfloat16 h; unsigned short u; } cv;
    cv.h = __float2bfloat16(f);
    return cv.u;
}
__device__ __forceinline__ float bfu2f(unsigned short u) {
    union { __hip_bfloat16 h; unsigned short u; } cv;
    cv.u = u;
    return __bfloat162float(cv.h);
}

// ---------- K0: prep, PARALLEL (1 wave per code): B-frags for 32x32x16 + f64 codebook ----------
// B (K16 x N32) frag layout: lane = col + 32*((k>>3)&1), elem j = k&7, K-step ks = k>>4.
// Frag index F = tile*8 + ks*2 + comp (comp: 0=hi, 1=lo); u16 index = (F*64 + lane)*8 + j.
__global__ __launch_bounds__(64) void k_prep(const float* __restrict__ emb,
                                             unsigned short* __restrict__ wB,
                                             double* __restrict__ eT,     // [64][1024] f64
                                             double* __restrict__ wB2D,
                                             int* __restrict__ counts,
                                             int* __restrict__ nflag,
                                             float* __restrict__ lossp) {
    const int c = blockIdx.x;                  // code (1024 blocks)
    const int i = threadIdx.x;                 // dim  (64 lanes)
    if (i == 0) counts[c] = 0;
    if (c == 0 && i == 0) { *nflag = 0; *lossp = 0.f; }

    float e = emb[(size_t)c * DIM + i];
    float sq = e * e;
    #pragma unroll
    for (int off = 1; off < 64; off <<= 1) sq += __shfl_xor(sq, off);
    float inv = 1.0f / fmaxf(sqrtf(sq), 1e-12f);
    float h = e * inv;
    unsigned short hi = f2bf_u(h);
    unsigned short lo = f2bf_u(h - bfu2f(hi));
    const int t = c >> 5, col = c & 31;
    const int ks = i >> 4, hh = (i >> 3) & 1, j = i & 7;
    const int ln = col + 32 * hh;
    wB[(((t*8 + ks*2 + 0) * 64) + ln) * 8 + j] = hi;
    wB[(((t*8 + ks*2 + 1) * 64) + ln) * 8 + j] = lo;

    double ed = (double)e;
    double sd = ed * ed;
    #pragma unroll
    for (int off = 1; off < 64; off <<= 1) sd += __shfl_xor(sd, off);
    double dnd = fmax(sqrt(sd), 1e-12);
    double eh  = ed / dnd;
    eT[(size_t)i * KC + c] = eh;
    double b2 = eh * eh;
    #pragma unroll
    for (int off = 1; off < 64; off <<= 1) b2 += __shfl_xor(b2, off);
    if (i == 0) wB2D[c] = b2;
}

// ---------- K1: 32x32x16 MFMA distances; barrier-free, direct L2->VGPR ----------
// acc = 1.5 - dot; 32 q/wave (M=32), 32 tiles of 32 codes, 12 MFMA/tile (half of 16x16).
// A (M32 x K16) layout: lane = m + 32*(k>>3 within step), i.e. m=lane&31, k=16*ks+8*(lane>>5)+j.
// C/D layout (HW-verified m74/m101): col=lane&31, row=(reg&3)+8*(reg>>2)+4*(lane>>5).
__global__ __launch_bounds__(256) void k_assign(const float* __restrict__ inp,
                                                const unsigned short* __restrict__ wB,
                                                float* __restrict__ idx_out,
                                                int* __restrict__ flag_list,
                                                int* __restrict__ nflag) {
    const int tid  = threadIdx.x;
    const int lane = tid & 63, wv = tid >> 6;
    const int m  = lane & 31;                  // query row / B col slot
    const int hh = lane >> 5;                  // k-half selector
    const int qbase = blockIdx.x * 128 + wv * 32;

    // A-frags: lane holds query (qbase+m), dims {16ks + 8hh + j}
    BF8 ah[4], al[4];
    {
        const float4* qp = reinterpret_cast<const float4*>(inp + (size_t)(qbase + m) * DIM);
        float x[32];
        #pragma unroll
        for (int ks = 0; ks < 4; ++ks) {
            float4 a = qp[4*ks + 2*hh];
            float4 b = qp[4*ks + 2*hh + 1];
            x[8*ks+0]=a.x; x[8*ks+1]=a.y; x[8*ks+2]=a.z; x[8*ks+3]=a.w;
            x[8*ks+4]=b.x; x[8*ks+5]=b.y; x[8*ks+6]=b.z; x[8*ks+7]=b.w;
        }
        float sq = 0.f;
        #pragma unroll
        for (int i = 0; i < 32; ++i) sq += x[i] * x[i];
        sq += __shfl_xor(sq, 32);              // partner lane has other 32 dims
        float ninv = -1.0f / fmaxf(sqrtf(sq), 1e-12f);   // NEGATED normalize
        #pragma unroll
        for (int ks = 0; ks < 4; ++ks)
            #pragma unroll
            for (int j = 0; j < 8; ++j) {
                float h = x[8*ks+j] * ninv;    // -x_hat
                unsigned short hi = f2bf_u(h);
                ah[ks].u[j] = hi;
                al[ks].u[j] = f2bf_u(h - bfu2f(hi));
            }
    }

    int best[16], best2[16];
    #pragma unroll
    for (int r = 0; r < 16; ++r) { best[r] = 0x7FFFFFFF; best2[r] = 0x7FFFFFFF; }

    // Barrier-free tile stream: 32 tiles x 8 frags, 1-tile software prefetch.
    const s8bf* wBs = reinterpret_cast<const s8bf*>(wB);
    s8bf nb0 = wBs[0*64 + lane], nb1 = wBs[1*64 + lane];
    s8bf nb2 = wBs[2*64 + lane], nb3 = wBs[3*64 + lane];
    s8bf nb4 = wBs[4*64 + lane], nb5 = wBs[5*64 + lane];
    s8bf nb6 = wBs[6*64 + lane], nb7 = wBs[7*64 + lane];

    for (int gt = 0; gt < 32; ++gt) {          // 32 tiles of 32 codes
        s8bf bh0 = nb0, bl0 = nb1, bh1 = nb2, bl1 = nb3;
        s8bf bh2 = nb4, bl2 = nb5, bh3 = nb6, bl3 = nb7;
        if (gt < 31) {                         // prefetch next tile
            const s8bf* p = wBs + (size_t)(gt + 1) * 8 * 64 + lane;
            nb0 = p[0];   nb1 = p[64];  nb2 = p[128]; nb3 = p[192];
            nb4 = p[256]; nb5 = p[320]; nb6 = p[384]; nb7 = p[448];
        }
        f32x16 acc = {1.5f,1.5f,1.5f,1.5f,1.5f,1.5f,1.5f,1.5f,
                      1.5f,1.5f,1.5f,1.5f,1.5f,1.5f,1.5f,1.5f};  // acc = 1.5 - dot
        acc = __builtin_amdgcn_mfma_f32_32x32x16_bf16(ah[0].v, bh0, acc, 0, 0, 0);
        acc = __builtin_amdgcn_mfma_f32_32x32x16_bf16(ah[1].v, bh1, acc, 0, 0, 0);
        acc = __builtin_amdgcn_mfma_f32_32x32x16_bf16(ah[2].v, bh2, acc, 0, 0, 0);
        acc = __builtin_amdgcn_mfma_f32_32x32x16_bf16(ah[3].v, bh3, acc, 0, 0, 0);
        acc = __builtin_amdgcn_mfma_f32_32x32x16_bf16(ah[0].v, bl0, acc, 0, 0, 0);
        acc = __builtin_amdgcn_mfma_f32_32x32x16_bf16(al[0].v, bh0, acc, 0, 0, 0);
        acc = __builtin_amdgcn_mfma_f32_32x32x16_bf16(ah[1].v, bl1, acc, 0, 0, 0);
        acc = __builtin_amdgcn_mfma_f32_32x32x16_bf16(al[1].v, bh1, acc, 0, 0, 0);
        acc = __builtin_amdgcn_mfma_f32_32x32x16_bf16(ah[2].v, bl2, acc, 0, 0, 0);
        acc = __builtin_amdgcn_mfma_f32_32x32x16_bf16(al[2].v, bh2, acc, 0, 0, 0);
        acc = __builtin_amdgcn_mfma_f32_32x32x16_bf16(ah[3].v, bl3, acc, 0, 0, 0);
        acc = __builtin_amdgcn_mfma_f32_32x32x16_bf16(al[3].v, bh3, acc, 0, 0, 0);
        #pragma unroll
        for (int r = 0; r < 16; ++r) {
            // 3-op update: and_or pack | med3 best2 | min best
            int p = (__float_as_int(acc[r]) & 0xFFFFFFC0) | gt;   // gt < 32 fits 6b
            int bo = best[r];
            int b2n;
            asm("v_med3_i32 %0, %1, %2, %3"
                : "=v"(b2n) : "v"(bo), "v"(best2[r]), "v"(p));
            best2[r] = b2n;                    // median(best, best2, p)
            best[r]  = min(bo, p);
        }
    }

    // 32-lane argmin reduce (within each k-half group: same queries); col carrier
    int colb[16];
    #pragma unroll
    for (int r = 0; r < 16; ++r) colb[r] = m;

    #pragma unroll
    for (int off = 1; off < 32; off <<= 1) {   // 5 steps, stays within 32-lane half
        #pragma unroll
        for (int r = 0; r < 16; ++r) {
            int ob  = __shfl_xor(best[r],  off);
            int ob2 = __shfl_xor(best2[r], off);
            int oc  = __shfl_xor(colb[r],  off);
            int bo  = best[r];
            colb[r]  = (ob < bo) ? oc : colb[r];   // ties keep self (flagged anyway)
            best[r]  = min(bo, ob);
            best2[r] = min(min(best2[r], ob2), max(bo, ob));
        }
    }
    #pragma unroll
    for (int r = 0; r < 16; ++r) {
        if (m == r) {                          // owner lane (one per half-group)
            int   q  = qbase + (r & 3) + 8 * (r >> 2) + 4 * hh;   // C/D row map
            int   pk = best[r];
            float a1 = __int_as_float(pk & 0xFFFFFFC0);           // acc-space
            float a2 = __int_as_float(best2[r] & 0xFFFFFFC0);
            int code = ((pk & 63) << 5) | colb[r];                // gt*32 + col
            idx_out[q] = (float)code;
            if (a2 - a1 < MARGIN_A) {          // ambiguous -> f64 rescue
                int slot = atomicAdd(nflag, 1);
                flag_list[slot] = q;
            }
        }
    }
}

// ---------- K2: f64 rescore, coalesced eT + 4 independent dot chains (proven) ----------
__global__ __launch_bounds__(256) void k_rescue(const float* __restrict__ inp,
                                                const double* __restrict__ eT,
                                                const double* __restrict__ wB2D,
                                                const int* __restrict__ flag_list,
                                                const int* __restrict__ nflag,
                                                float* __restrict__ idx_out) {
    __shared__ double xh[DIM];
    __shared__ double Ash;
    __shared__ double sdw[4];
    __shared__ int    siw[4];
    const int tid = threadIdx.x;
    const int lane = tid & 63, wv = tid >> 6;
    const int n = *nflag;

    for (int j = blockIdx.x; j < n; j += gridDim.x) {   // uniform trip per block
        const int q = flag_list[j];
        if (tid < 64) {
            double xv = (double)inp[(size_t)q * DIM + tid];
            double s = xv * xv;
            #pragma unroll
            for (int off = 32; off; off >>= 1) s += __shfl_xor(s, off);
            double dn = fmax(sqrt(s), 1e-12);
            double h  = xv / dn;
            xh[tid] = h;
            double a = h * h;
            #pragma unroll
            for (int off = 32; off; off >>= 1) a += __shfl_xor(a, off);
            if (tid == 0) Ash = a;
        }
        __syncthreads();
        const double A = Ash;

        double dot0 = 0.0, dot1 = 0.0, dot2 = 0.0, dot3 = 0.0;
        #pragma unroll 8
        for (int i = 0; i < DIM; ++i) {
            double xi = xh[i];                           // LDS broadcast
            const double* row = eT + (size_t)i * KC + tid;
            dot0 += xi * row[0];
            dot1 += xi * row[256];
            dot2 += xi * row[512];
            dot3 += xi * row[768];
        }
        double bd = 1e300; int bi = 1 << 30;
        double d0 = (A + wB2D[tid      ]) - 2.0 * dot0;
        double d1 = (A + wB2D[tid + 256]) - 2.0 * dot1;
        double d2 = (A + wB2D[tid + 512]) - 2.0 * dot2;
        double d3 = (A + wB2D[tid + 768]) - 2.0 * dot3;
        if (d0 < bd) { bd = d0; bi = tid;       }        // ascending c: first-min
        if (d1 < bd) { bd = d1; bi = tid + 256; }
        if (d2 < bd) { bd = d2; bi = tid + 512; }
        if (d3 < bd) { bd = d3; bi = tid + 768; }
        #pragma unroll
        for (int off = 1; off < 64; off <<= 1) {         // 64-lane (d,i) min-reduce
            double od = __shfl_xor(bd, off);
            int    oi = __shfl_xor(bi, off);
            if (od < bd || (od == bd && oi < bi)) { bd = od; bi = oi; }
        }
        if (lane == 0) { sdw[wv] = bd; siw[wv] = bi; }
        __syncthreads();
        if (tid == 0) {
            double B = sdw[0]; int I = siw[0];
            #pragma unroll
            for (int i = 1; i < 4; ++i)
                if (sdw[i] < B || (sdw[i] == B && siw[i] < I)) { B = sdw[i]; I = siw[i]; }
            idx_out[q] = (float)I;                       // final
        }
        __syncthreads();
    }
}

// ---------- K3: gather (f32 out) + sum((q-f)^2) + FUSED histogram ----------
__global__ __launch_bounds__(256) void k_gather_loss(const float* __restrict__ inp,
                                                     const float* __restrict__ emb,
                                                     const float* __restrict__ idx_out,
                                                     float* __restrict__ qout,
                                                     float* __restrict__ loss,
                                                     int* __restrict__ counts) {
    __shared__ int h[KC];
    const int tid = threadIdx.x;
    for (int i = tid; i < KC; i += 256) h[i] = 0;
    __syncthreads();

    const int gid = blockIdx.x * 256 + tid;            // 524288 threads, 4 iters each
    float lsum = 0.f;
    for (int e4 = gid; e4 < NQ * 16; e4 += 524288) {
        int   qi = e4 >> 4;
        int   d4 = e4 & 15;
        int   k  = ((int)idx_out[qi]) & (KC - 1);
        float4 qv = reinterpret_cast<const float4*>(emb + (size_t)k * DIM)[d4];
        float4 fv = reinterpret_cast<const float4*>(inp)[e4];
        float ux = qv.x - fv.x, uy = qv.y - fv.y, uz = qv.z - fv.z, uw = qv.w - fv.w;
        lsum += ux*ux + uy*uy + uz*uz + uw*uw;
        reinterpret_cast<float4*>(qout)[e4] = qv;
        if (d4 == 0) atomicAdd(&h[k], 1);              // count each query once
    }
    __syncthreads();                                   // hist adds done
    for (int i = tid; i < KC; i += 256) {
        int v = h[i];
        if (v) atomicAdd(&counts[i], v);
    }
    #pragma unroll
    for (int off = 32; off; off >>= 1) lsum += __shfl_xor(lsum, off);
    __shared__ float wsum[4];
    int wid = tid >> 6, lane = tid & 63;
    if (lane == 0) wsum[wid] = lsum;
    __syncthreads();
    if (tid == 0)
        atomicAdd(loss, (wsum[0] + wsum[1]) + (wsum[2] + wsum[3]));
}

// ---------- K4: perplexity / usage / vq_loss ----------
__global__ __launch_bounds__(1024) void k_stats2(const int* __restrict__ counts,
                                                 float* __restrict__ out3) {
    int t = threadIdx.x;
    int c = counts[t];
    float p    = (float)c * (1.0f / (float)NQ);
    float ent  = p * logf(p + 1e-10f);
    float used = (c > 0) ? 1.0f : 0.0f;
    #pragma unroll
    for (int off = 32; off; off >>= 1) {
        ent  += __shfl_xor(ent, off);
        used += __shfl_xor(used, off);
    }
    __shared__ float se[16], su[16];
    int w = t >> 6, l = t & 63;
    if (l == 0) { se[w] = ent; su[w] = used; }
    __syncthreads();
    if (t == 0) {
        float E = 0.f, U = 0.f;
        #pragma unroll
        for (int i = 0; i < 16; ++i) { E += se[i]; U += su[i]; }
        float L = out3[0];                             // loss accumulated here
        out3[0] = L * 1.25f / 8388608.0f;              // vq_loss (q + 0.25*e)
        out3[1] = expf(-E);                            // perplexity
        out3[2] = U * (1.0f / 1024.0f);                // codebook_usage
    }
}

// ---------- launch (5 kernels) ----------
// d_out (f32, 8519683): [0,8388608) quantized | [8388608,8519680) idx | 3 scalars
// Scratch in the quantized region (consumed by k_rescue, overwritten by gather):
//   flag_list @ float 0 (<=512 KB) | eT f64[64][1024] @ float 1048576 (512 KB)
// d_ws: counts[1024]@0 | wB u16[131072]@4096 | wB2D f64[1024]@266240 | nflag@274432
extern "C" void kernel_launch(void* const* d_in, const int* in_sizes, int n_in,
                              void* d_out, int out_size, void* d_ws, size_t ws_size,
                              hipStream_t stream) {
    const float* inp = (const float*)d_in[0];   // [32,4096,64] f32
    const float* emb = (const float*)d_in[1];   // [1024,64] f32

    float*  qout      = (float*)d_out;
    int*    flag_list = (int*)d_out;                        // quantized region, part 1
    double* eT        = (double*)((float*)d_out + 1048576); // quantized region, part 2
    float*  idx_out   = (float*)d_out + 8388608;
    float*  out3      = (float*)d_out + 8519680;

    int*            counts = (int*)d_ws;
    unsigned short* wB     = (unsigned short*)((char*)d_ws + 4096);
    double*         wB2D   = (double*)((char*)d_ws + 266240);
    int*            nflag  = (int*)((char*)d_ws + 274432);

    hipLaunchKernelGGL(k_prep,        dim3(1024), dim3(64),   0, stream,
                       emb, wB, eT, wB2D, counts, nflag, out3);
    hipLaunchKernelGGL(k_assign,      dim3(1024), dim3(256),  0, stream,
                       inp, wB, idx_out, flag_list, nflag);
    hipLaunchKernelGGL(k_rescue,      dim3(RGRID), dim3(256), 0, stream,
                       inp, eT, wB2D, flag_list, nflag, idx_out);
    hipLaunchKernelGGL(k_gather_loss, dim3(2048), dim3(256),  0, stream,
                       inp, emb, idx_out, qout, out3, counts);
    hipLaunchKernelGGL(k_stats2,      dim3(1),    dim3(1024), 0, stream, counts, out3);
}